// Round 1
// baseline (167.536 us; speedup 1.0000x reference)
//
#include <hip/hip_runtime.h>
#include <hip/hip_bf16.h>
#include <type_traits>

// Windowed attention smoothing via MFMA — barrier-free, per-wave autonomous,
// software-pipelined across block-tiles.
// rows=200000, RANK=64, WINDOW=11. Block=256 (4 waves), 16 rows/wave/tile,
// persistent grid-stride loop over 64-row block-tiles.
//
// v2 changes vs 135.6us baseline (latency-bound theory):
//   1. Interior tiles (bt>0 && bt*64+69<=rows) compile with ZERO bounds
//      guards (template<GUARDED>). Only first/last tile pay guard cost.
//   2. aw[26] fp32 window loads hoisted above tanh/M2/softmax so their
//      HBM/L2 latency hides under dependent compute.
//   3. Next tile's A-fragments (abnd/am1) prefetched right after M2
//      consumes the current ones -> next-tile load latency hides under
//      softmax + P4 (~1000 cy). Register rotation statically indexed.
// No __syncthreads anywhere: LDS regions are wave-private; DS pipe is
// in-order within a wave.

constexpr int RANK   = 64;
constexpr int WINDOW = 11;
constexpr int PAD    = 5;
constexpr int TILE   = 16;   // rows per wave
constexpr int BLOCK  = 256;  // 4 waves
constexpr int TR     = 64;   // rows per block-tile

typedef short short8  __attribute__((ext_vector_type(8)));
typedef float float4v __attribute__((ext_vector_type(4)));

constexpr int V1_S = 72;  // bf16 elems per V1 row (144B, 16B-aligned)
constexpr int SC_S = 18;  // f32 elems per Sc row (breaks pow2, writes <=2-way)

__device__ __forceinline__ short8 cvt_bf8(float4 a, float4 b) {
    union { short8 s; __hip_bfloat162 h[4]; } u;
    u.h[0] = __float22bfloat162_rn(make_float2(a.x, a.y));
    u.h[1] = __float22bfloat162_rn(make_float2(a.z, a.w));
    u.h[2] = __float22bfloat162_rn(make_float2(b.x, b.y));
    u.h[3] = __float22bfloat162_rn(make_float2(b.z, b.w));
    return u.s;
}

// Guarded fragment load (used for first/last tiles and all prefetches;
// OOB rows -> zeros, matching jnp.pad semantics).
__device__ __forceinline__ short8 load_afrag_g(const float* __restrict__ A,
                                               int row, int col0, int rows) {
    if ((unsigned)row < (unsigned)rows) {
        const float4* p = (const float4*)(A + (size_t)row * RANK + col0);
        return cvt_bf8(p[0], p[1]);
    }
    return (short8)0;
}

__device__ __forceinline__ float fast_tanh(float x) {
    return 1.0f - 2.0f / (1.0f + __expf(2.0f * x));
}

__global__ __launch_bounds__(BLOCK, 4) void attn_win_kernel(
    const float* __restrict__ A,   // (rows, 64)
    const float* __restrict__ W,   // (64, 64) row-major (out,in)
    const float* __restrict__ b,   // (64,)
    float* __restrict__ out,       // (rows, 64)
    int rows)
{
    __shared__ __align__(16) __hip_bfloat16 V1[4][TILE][V1_S];  // 9216 B
    __shared__ __align__(16) float          Sc[4][32][SC_S];    // 9216 B

    const int lane = threadIdx.x & 63;
    const int wv   = threadIdx.x >> 6;
    const int m16  = lane & 15;
    const int quad = lane >> 4;

    // ---- Persistent W fragments (32 VGPRs) + bias, converted ONCE per wave ----
    short8 wfrag[4][2];  // [ct][kf]: W[n=ct*16+m16][kf*32 + quad*8 + j]
    #pragma unroll
    for (int ct = 0; ct < 4; ct++) {
        #pragma unroll
        for (int kf = 0; kf < 2; kf++) {
            const float4* p =
                (const float4*)(W + (ct * 16 + m16) * RANK + kf * 32 + quad * 8);
            wfrag[ct][kf] = cvt_bf8(p[0], p[1]);
        }
    }
    float bias[4];
    #pragma unroll
    for (int ct = 0; ct < 4; ct++) bias[ct] = b[ct * 16 + m16];

    const int n_btiles = (rows + TR - 1) / TR;

    int bt = blockIdx.x;
    if (bt >= n_btiles) return;

    // ---- prologue: load first tile's fragments (always guarded) ----
    short8 abnd[2][2];  // band rows rw-5+it*16+m16 (band idx i=it*16+m16)
    short8 am1[2];      // M1 rows rw+m16
    {
        const int rw0 = bt * TR + wv * TILE;
        #pragma unroll
        for (int it = 0; it < 2; it++)
            #pragma unroll
            for (int kf = 0; kf < 2; kf++)
                abnd[it][kf] = load_afrag_g(A, rw0 - PAD + it * 16 + m16,
                                            kf * 32 + quad * 8, rows);
        #pragma unroll
        for (int kf = 0; kf < 2; kf++)
            am1[kf] = load_afrag_g(A, rw0 + m16, kf * 32 + quad * 8, rows);
    }

    for (; bt < n_btiles; bt += gridDim.x) {
        const int rw  = bt * TR + wv * TILE;   // this wave's rows rw..rw+15
        const int bt2 = bt + gridDim.x;
        const int rw2 = bt2 * TR + wv * TILE;  // next tile's rows (may be OOB)

        auto body = [&](auto GC) {
            constexpr bool G = decltype(GC)::value;

            // ---- M1: V1 = tanh(A[rw..rw+15] @ W^T + b) ----
            float4v acc[4];
            #pragma unroll
            for (int ct = 0; ct < 4; ct++)
                acc[ct] = (float4v){bias[ct], bias[ct], bias[ct], bias[ct]};
            #pragma unroll
            for (int kf = 0; kf < 2; kf++)
                #pragma unroll
                for (int ct = 0; ct < 4; ct++)
                    acc[ct] = __builtin_amdgcn_mfma_f32_16x16x32_bf16(
                        am1[kf], wfrag[ct][kf], acc[ct], 0, 0, 0);

            // ---- current tile's fp32 window loads, issued HERE so their
            //      latency hides under tanh + M2 + softmax ----
            float aw[26];
            #pragma unroll
            for (int s = 0; s < 26; s++) {
                const int gr = rw - PAD + s;
                if (!G || (unsigned)gr < (unsigned)rows)
                    aw[s] = A[(size_t)gr * RANK + lane];
                else
                    aw[s] = 0.0f;
            }

            // M1 epilogue: element (row q=quad*4+rg, col c=ct*16+m16)
            #pragma unroll
            for (int ct = 0; ct < 4; ct++)
                #pragma unroll
                for (int rg = 0; rg < 4; rg++)
                    V1[wv][quad * 4 + rg][ct * 16 + m16] =
                        __float2bfloat16(fast_tanh(acc[ct][rg]));

            // ---- M2: S[i][q] = dot(Aband[i], v1[q]) ----
            float4v sacc[2];
            sacc[0] = (float4v){0.f, 0.f, 0.f, 0.f};
            sacc[1] = (float4v){0.f, 0.f, 0.f, 0.f};
            #pragma unroll
            for (int kf = 0; kf < 2; kf++) {
                const short8 bfr =
                    *(const short8*)&V1[wv][m16][kf * 32 + quad * 8];
                #pragma unroll
                for (int it = 0; it < 2; it++)
                    sacc[it] = __builtin_amdgcn_mfma_f32_16x16x32_bf16(
                        abnd[it][kf], bfr, sacc[it], 0, 0, 0);
            }
            // scatter S (i = it*16+quad*4+rg, q = m16); rows 26..31 are dead
            #pragma unroll
            for (int it = 0; it < 2; it++)
                #pragma unroll
                for (int rg = 0; rg < 4; rg++)
                    Sc[wv][it * 16 + quad * 4 + rg][m16] = sacc[it][rg];

            // ---- prefetch NEXT tile's fragments (abnd/am1 dead after M2);
            //      latency hides under softmax + P4. Always guarded: when
            //      bt2 >= n_btiles every lane is OOB -> exec-masked no-op. ----
            #pragma unroll
            for (int it = 0; it < 2; it++)
                #pragma unroll
                for (int kf = 0; kf < 2; kf++)
                    abnd[it][kf] = load_afrag_g(A, rw2 - PAD + it * 16 + m16,
                                                kf * 32 + quad * 8, rows);
            #pragma unroll
            for (int kf = 0; kf < 2; kf++)
                am1[kf] = load_afrag_g(A, rw2 + m16, kf * 32 + quad * 8, rows);

            // ---- softmax over band i in [q, q+10] of column q=m16 ----
            // (redundant across quads; broadcast LDS reads; lane rr holds
            //  row rw+rr's probabilities)
            float p[WINDOW];
            {
                float s[WINDOW];
                float mx = -1e30f;
                #pragma unroll
                for (int w = 0; w < WINDOW; w++) {
                    s[w] = Sc[wv][m16 + w][m16];
                    mx = fmaxf(mx, s[w]);
                }
                float den = 0.0f;
                #pragma unroll
                for (int w = 0; w < WINDOW; w++) {
                    p[w] = __expf((s[w] - mx) * 0.125f);  // 1/sqrt(64) folded
                    den += p[w];
                }
                const float rden = __fdividef(1.0f, den);
                #pragma unroll
                for (int w = 0; w < WINDOW; w++) p[w] *= rden;
            }

            // ---- P4: out[rw+rr][lane] = sum_w p[rr][w] * aw[rr+w] ----
            #pragma unroll
            for (int rr = 0; rr < TILE; rr++) {
                float o = 0.0f;
                #pragma unroll
                for (int w = 0; w < WINDOW; w++) {
                    const float pw = __uint_as_float(
                        __builtin_amdgcn_readlane(__float_as_uint(p[w]), rr));
                    o = fmaf(pw, aw[rr + w], o);
                }
                if (!G || rw + rr < rows)
                    out[(size_t)(rw + rr) * RANK + lane] = o;
            }
        };

        // Interior iff block touches no row < 0 (bt>0) and none >= rows:
        // max row touched by template-guarded code = bt*TR + 48 + 20.
        const bool interior = (bt > 0) && (bt * TR + TR + PAD + 20 <= rows);
        if (interior)
            body(std::integral_constant<bool, false>{});
        else
            body(std::integral_constant<bool, true>{});
    }
}

extern "C" void kernel_launch(void* const* d_in, const int* in_sizes, int n_in,
                              void* d_out, int out_size, void* d_ws, size_t ws_size,
                              hipStream_t stream) {
    const float* A = (const float*)d_in[0];
    const float* W = (const float*)d_in[1];
    const float* b = (const float*)d_in[2];
    float* out = (float*)d_out;

    const int rows     = in_sizes[0] / RANK;
    const int n_btiles = (rows + TR - 1) / TR;
    const int blocks   = n_btiles < 1024 ? n_btiles : 1024;  // persistent

    hipLaunchKernelGGL(attn_win_kernel, dim3(blocks), dim3(BLOCK), 0, stream,
                       A, W, b, out, rows);
}

// Round 2
// 117.171 us; speedup vs baseline: 1.4298x; 1.4298x over previous
//
#include <hip/hip_runtime.h>
#include <hip/hip_bf16.h>

// Windowed attention smoothing via MFMA — barrier-free, per-wave autonomous.
// v3: wave-private LDS band staging (fp32, 32 rows/tile), reg-staged with
// async-split prefetch of the next tile (T14). All fragment/aw reads come
// from LDS; global traffic drops to 2x A-read + 1x write. No __syncthreads:
// LDS regions are wave-private and the DS pipe is in-order within a wave.
//
// rows=200000, RANK=64, WINDOW=11. Block=256 (4 waves), 16 rows/wave/tile,
// persistent grid-stride loop over 64-row block-tiles, grid=768 (3 blk/CU).

constexpr int RANK   = 64;
constexpr int WINDOW = 11;
constexpr int PAD    = 5;
constexpr int TILE   = 16;   // rows per wave
constexpr int BLOCK  = 256;  // 4 waves
constexpr int TR     = 64;   // rows per block-tile
constexpr int BSTR   = 68;   // band row stride (floats): 272B = 16B-aligned,
                             // bank start advances 4/row -> conflict-free-ish
constexpr int GRIDB  = 768;  // 3 resident blocks/CU x 256 CU (LDS-capped)

typedef short short8  __attribute__((ext_vector_type(8)));
typedef float float4v __attribute__((ext_vector_type(4)));

constexpr int V1_S = 72;  // bf16 elems per V1 row (144B, 16B-aligned)
constexpr int SC_S = 18;  // f32 elems per Sc row (breaks pow2)

__device__ __forceinline__ short8 cvt_bf8(float4 a, float4 b) {
    union { short8 s; __hip_bfloat162 h[4]; } u;
    u.h[0] = __float22bfloat162_rn(make_float2(a.x, a.y));
    u.h[1] = __float22bfloat162_rn(make_float2(a.z, a.w));
    u.h[2] = __float22bfloat162_rn(make_float2(b.x, b.y));
    u.h[3] = __float22bfloat162_rn(make_float2(b.z, b.w));
    return u.s;
}

__device__ __forceinline__ float fast_tanh(float x) {
    return 1.0f - 2.0f / (1.0f + __expf(2.0f * x));
}

__global__ __launch_bounds__(BLOCK, 3) void attn_win_kernel(
    const float* __restrict__ A,   // (rows, 64)
    const float* __restrict__ W,   // (64, 64) row-major (out,in)
    const float* __restrict__ b,   // (64,)
    float* __restrict__ out,       // (rows, 64)
    int rows)
{
    // Per-wave LDS: 8704 (band) + 2304 (V1) + 2304 (Sc) = 13312 B; x4 = 53248 B
    __shared__ __align__(16) float          band[4][32][BSTR];
    __shared__ __align__(16) __hip_bfloat16 V1[4][TILE][V1_S];
    __shared__ __align__(16) float          Sc[4][32][SC_S];

    const int lane = threadIdx.x & 63;
    const int wv   = threadIdx.x >> 6;
    const int m16  = lane & 15;
    const int quad = lane >> 4;
    const int sr   = lane >> 4;        // staging: row-within-group-of-4
    const int sc4  = (lane & 15) * 4;  // staging: starting col (float4)

    // ---- Persistent W fragments (32 VGPRs) + bias, converted ONCE per wave ----
    short8 wfrag[4][2];  // [ct][kf]: W[n=ct*16+m16][kf*32 + quad*8 + j]
    #pragma unroll
    for (int ct = 0; ct < 4; ct++) {
        #pragma unroll
        for (int kf = 0; kf < 2; kf++) {
            const float4* p =
                (const float4*)(W + (ct * 16 + m16) * RANK + kf * 32 + quad * 8);
            wfrag[ct][kf] = cvt_bf8(p[0], p[1]);
        }
    }
    float bias[4];
    #pragma unroll
    for (int ct = 0; ct < 4; ct++) bias[ct] = b[ct * 16 + m16];

    const int n_btiles = (rows + TR - 1) / TR;
    int bt = blockIdx.x;
    if (bt >= n_btiles) return;

    // ---- prologue: stage FIRST tile's 32-row fp32 band into LDS ----
    // (OOB rows -> zeros, matching jnp.pad semantics; covers bt=0 and tail)
    {
        const int rw0 = bt * TR + wv * TILE;
        float4 stg[8];
        #pragma unroll
        for (int j = 0; j < 8; j++) {
            const int g = rw0 - PAD + j * 4 + sr;
            stg[j] = ((unsigned)g < (unsigned)rows)
                         ? *(const float4*)(A + (size_t)g * RANK + sc4)
                         : make_float4(0.f, 0.f, 0.f, 0.f);
        }
        #pragma unroll
        for (int j = 0; j < 8; j++)
            *(float4*)&band[wv][j * 4 + sr][sc4] = stg[j];
    }

    for (; bt < n_btiles; bt += gridDim.x) {
        const int rw = bt * TR + wv * TILE;   // this wave's rows rw..rw+15

        // ---- MFMA fragments from LDS band (fp32 -> bf16 in regs) ----
        // band[i] = A[rw-5+i]; abnd rows i=it*16+m16; am1 rows i=5+m16
        short8 abnd[2][2];
        short8 am1[2];
        #pragma unroll
        for (int it = 0; it < 2; it++)
            #pragma unroll
            for (int kf = 0; kf < 2; kf++) {
                const float4* pp =
                    (const float4*)&band[wv][it * 16 + m16][kf * 32 + quad * 8];
                abnd[it][kf] = cvt_bf8(pp[0], pp[1]);
            }
        #pragma unroll
        for (int kf = 0; kf < 2; kf++) {
            const float4* pp =
                (const float4*)&band[wv][PAD + m16][kf * 32 + quad * 8];
            am1[kf] = cvt_bf8(pp[0], pp[1]);
        }

        // ---- issue NEXT tile's global loads NOW; HBM latency hides under
        //      M1 + M2 + softmax. ds_write happens after current band's
        //      last read (aw). Guarded: past-the-end tiles load zeros. ----
        float4 stg[8];
        {
            const int rwn = (bt + (int)gridDim.x) * TR + wv * TILE;
            #pragma unroll
            for (int j = 0; j < 8; j++) {
                const int g = rwn - PAD + j * 4 + sr;
                stg[j] = ((unsigned)g < (unsigned)rows)
                             ? *(const float4*)(A + (size_t)g * RANK + sc4)
                             : make_float4(0.f, 0.f, 0.f, 0.f);
            }
        }

        // ---- M1: V1 = tanh(A[rw..rw+15] @ W^T + b) ----
        float4v acc[4];
        #pragma unroll
        for (int ct = 0; ct < 4; ct++)
            acc[ct] = (float4v){bias[ct], bias[ct], bias[ct], bias[ct]};
        #pragma unroll
        for (int kf = 0; kf < 2; kf++)
            #pragma unroll
            for (int ct = 0; ct < 4; ct++)
                acc[ct] = __builtin_amdgcn_mfma_f32_16x16x32_bf16(
                    am1[kf], wfrag[ct][kf], acc[ct], 0, 0, 0);
        // epilogue: element (row q=quad*4+rg, col c=ct*16+m16) -> V1[q][c]
        #pragma unroll
        for (int ct = 0; ct < 4; ct++)
            #pragma unroll
            for (int rg = 0; rg < 4; rg++)
                V1[wv][quad * 4 + rg][ct * 16 + m16] =
                    __float2bfloat16(fast_tanh(acc[ct][rg]));

        // ---- M2: S[i][q] = dot(band[i], v1[q]) ----
        float4v sacc[2];
        sacc[0] = (float4v){0.f, 0.f, 0.f, 0.f};
        sacc[1] = (float4v){0.f, 0.f, 0.f, 0.f};
        #pragma unroll
        for (int kf = 0; kf < 2; kf++) {
            const short8 bfr =
                *(const short8*)&V1[wv][m16][kf * 32 + quad * 8];
            #pragma unroll
            for (int it = 0; it < 2; it++)
                sacc[it] = __builtin_amdgcn_mfma_f32_16x16x32_bf16(
                    abnd[it][kf], bfr, sacc[it], 0, 0, 0);
        }
        // scatter S (i = it*16+quad*4+rg, q = m16); rows 26..31 are dead
        #pragma unroll
        for (int it = 0; it < 2; it++)
            #pragma unroll
            for (int rg = 0; rg < 4; rg++)
                Sc[wv][it * 16 + quad * 4 + rg][m16] = sacc[it][rg];

        // ---- softmax over band i in [q, q+10] of column q=m16 ----
        // (redundant across quads; lane rr<16 holds row rw+rr's probs)
        float p[WINDOW];
        {
            float s[WINDOW];
            float mx = -1e30f;
            #pragma unroll
            for (int w = 0; w < WINDOW; w++) {
                s[w] = Sc[wv][m16 + w][m16];
                mx = fmaxf(mx, s[w]);
            }
            float den = 0.0f;
            #pragma unroll
            for (int w = 0; w < WINDOW; w++) {
                p[w] = __expf((s[w] - mx) * 0.125f);  // 1/sqrt(64) folded in
                den += p[w];
            }
            const float rden = __fdividef(1.0f, den);
            #pragma unroll
            for (int w = 0; w < WINDOW; w++) p[w] *= rden;
        }

        // ---- aw: fp32 window from LDS band (last reads of current band) ----
        // lane reads band[s][lane]: banks (4s+lane)%32 -> 2-way, free
        float aw[26];
        #pragma unroll
        for (int s = 0; s < 26; s++) aw[s] = band[wv][s][lane];

        // ---- overwrite band with NEXT tile's rows. Safe: DS pipe is
        //      in-order within a wave, all current-band reads issued above. ----
        #pragma unroll
        for (int j = 0; j < 8; j++)
            *(float4*)&band[wv][j * 4 + sr][sc4] = stg[j];

        // ---- P4: out[rw+rr][lane] = sum_w p[rr][w] * aw[rr+w] ----
        #pragma unroll
        for (int rr = 0; rr < TILE; rr++) {
            float o = 0.0f;
            #pragma unroll
            for (int w = 0; w < WINDOW; w++) {
                const float pw = __uint_as_float(
                    __builtin_amdgcn_readlane(__float_as_uint(p[w]), rr));
                o = fmaf(pw, aw[rr + w], o);
            }
            if (rw + rr < rows)   // wave-uniform scalar guard
                out[(size_t)(rw + rr) * RANK + lane] = o;
        }
    }
}

extern "C" void kernel_launch(void* const* d_in, const int* in_sizes, int n_in,
                              void* d_out, int out_size, void* d_ws, size_t ws_size,
                              hipStream_t stream) {
    const float* A = (const float*)d_in[0];
    const float* W = (const float*)d_in[1];
    const float* b = (const float*)d_in[2];
    float* out = (float*)d_out;

    const int rows     = in_sizes[0] / RANK;
    const int n_btiles = (rows + TR - 1) / TR;
    const int blocks   = n_btiles < GRIDB ? n_btiles : GRIDB;  // persistent

    hipLaunchKernelGGL(attn_win_kernel, dim3(blocks), dim3(BLOCK), 0, stream,
                       A, W, b, out, rows);
}